// Round 1
// baseline (143.593 us; speedup 1.0000x reference)
//
#include <hip/hip_runtime.h>
#include <hip/hip_bf16.h>

#define SS 2048
#define DD 128
#define BB 16
#define LDST 136  // 128 + 8 ushort pad: b128 frag reads land 2-way on banks (free)

typedef short bf16x8 __attribute__((ext_vector_type(8)));
typedef float f32x4 __attribute__((ext_vector_type(4)));

__device__ __forceinline__ unsigned short f2bf(float f) {
  union { float f; unsigned u; } v; v.f = f;
  unsigned r = v.u + 0x7fffu + ((v.u >> 16) & 1u);  // RNE
  return (unsigned short)(r >> 16);
}
__device__ __forceinline__ float fexp2(float x) { return __builtin_amdgcn_exp2f(x); }

// ---------------------------------------------------------------------------
// Kernel 1: qk = x @ [Wq*log2e/sqrt(U) | Wk]  -> bf16 qb, kb (row-major S x 128)
// grid 256 (M/128), block 256 (4 waves); wave w: rows [w*32,+32) x all 256 n
// ---------------------------------------------------------------------------
__global__ __launch_bounds__(256) void qk_gemm(
    const float* __restrict__ x, const float* __restrict__ Wq,
    const float* __restrict__ Wk, unsigned short* __restrict__ qb,
    unsigned short* __restrict__ kb) {
  __shared__ unsigned short wt[256 * LDST];  // [n][k] = W^T, n<128:q-proj
  __shared__ unsigned short xa[128 * LDST];  // [m][k]
  const int tid = threadIdx.x, wave = tid >> 6, lane = tid & 63;
  const int lq = lane & 15, quad = lane >> 4;
  const int m0 = blockIdx.x * 128;
  const float qscale = 0.1275174346f;  // log2(e)/sqrt(128)

  for (int i = 0; i < 64; ++i) {  // stage+transpose both W (16384 elems each)
    int idx = i * 256 + tid;
    int d = idx >> 7, u = idx & 127;
    wt[u * LDST + d] = f2bf(Wq[idx] * qscale);
    wt[(u + 128) * LDST + d] = f2bf(Wk[idx]);
  }
#pragma unroll
  for (int i = 0; i < 16; ++i) {  // stage x tile 128x128 fp32 -> bf16
    int c4 = i * 256 + tid;
    int row = c4 >> 5, col = (c4 & 31) * 4;
    const float4 v = *(const float4*)(x + (size_t)(m0 + row) * DD + col);
    ushort4 h;
    h.x = f2bf(v.x); h.y = f2bf(v.y); h.z = f2bf(v.z); h.w = f2bf(v.w);
    *(ushort4*)(&xa[row * LDST + col]) = h;
  }
  __syncthreads();

  f32x4 acc[2][16];
#pragma unroll
  for (int mt = 0; mt < 2; ++mt)
#pragma unroll
    for (int nt = 0; nt < 16; ++nt) acc[mt][nt] = (f32x4){0.f, 0.f, 0.f, 0.f};

#pragma unroll
  for (int ks = 0; ks < 4; ++ks) {
    bf16x8 a0 = *(const bf16x8*)(&xa[(wave * 32 + lq) * LDST + ks * 32 + quad * 8]);
    bf16x8 a1 = *(const bf16x8*)(&xa[(wave * 32 + 16 + lq) * LDST + ks * 32 + quad * 8]);
#pragma unroll
    for (int nt = 0; nt < 16; ++nt) {
      bf16x8 bfr = *(const bf16x8*)(&wt[(nt * 16 + lq) * LDST + ks * 32 + quad * 8]);
      acc[0][nt] = __builtin_amdgcn_mfma_f32_16x16x32_bf16(a0, bfr, acc[0][nt], 0, 0, 0);
      acc[1][nt] = __builtin_amdgcn_mfma_f32_16x16x32_bf16(a1, bfr, acc[1][nt], 0, 0, 0);
    }
  }
  // epilogue: C/D layout col=lane&15, row=quad*4+r
#pragma unroll
  for (int mt = 0; mt < 2; ++mt)
#pragma unroll
    for (int nt = 0; nt < 16; ++nt)
#pragma unroll
      for (int r = 0; r < 4; ++r) {
        int grow = m0 + wave * 32 + mt * 16 + quad * 4 + r;
        unsigned short hv = f2bf(acc[mt][nt][r]);
        if (nt < 8) qb[(size_t)grow * DD + nt * 16 + lq] = hv;
        else        kb[(size_t)grow * DD + (nt - 8) * 16 + lq] = hv;
      }
}

// ---------------------------------------------------------------------------
// Kernel 2: per (b, 64-row i-block): pass1 l_i = sum_j exp2(s2_ij);
// c_i = sigmoid(theta-mu*t)/l_i; pass2 w_j += sum_i c_i*exp2(s2_ij)  (atomics)
// grid 16*32=512, block 256. wave w owns cols [w*32,+32) of each 128-col j-tile.
// ---------------------------------------------------------------------------
__global__ __launch_bounds__(256, 2) void attn_ce(
    const unsigned short* __restrict__ qb, const unsigned short* __restrict__ kb,
    const float* __restrict__ t, const float* __restrict__ theta,
    const float* __restrict__ mu, float* __restrict__ w) {
  const int b = blockIdx.x >> 5;
  const int i0 = (blockIdx.x & 31) * 64;
  const int tid = threadIdx.x, wave = tid >> 6, lane = tid & 63;
  const int lq = lane & 15, quad = lane >> 4;

  __shared__ unsigned short qs[64 * LDST];
  __shared__ unsigned short kt[128 * LDST];
  __shared__ float rs_lds[4][64];
  __shared__ float c_lds[64];

#pragma unroll
  for (int i = 0; i < 4; ++i) {  // stage q block 64x128 bf16
    int c8 = i * 256 + tid;
    int row = c8 >> 4, col = (c8 & 15) * 8;
    *(uint4*)(&qs[row * LDST + col]) =
        *(const uint4*)(qb + (size_t)(b * SS + i0 + row) * DD + col);
  }
  __syncthreads();

  // A-fragments register-resident for both passes: 64 rows x K=128
  bf16x8 af[4][4];
#pragma unroll
  for (int mt = 0; mt < 4; ++mt)
#pragma unroll
    for (int ks = 0; ks < 4; ++ks)
      af[mt][ks] = *(const bf16x8*)(&qs[(mt * 16 + lq) * LDST + ks * 32 + quad * 8]);

  auto stage_k = [&](int jt) {
#pragma unroll
    for (int i = 0; i < 8; ++i) {
      int c8 = i * 256 + tid;
      int row = c8 >> 4, col = (c8 & 15) * 8;
      *(uint4*)(&kt[row * LDST + col]) =
          *(const uint4*)(kb + (size_t)(b * SS + jt * 128 + row) * DD + col);
    }
  };

  float rowsum[4][4];
#pragma unroll
  for (int mt = 0; mt < 4; ++mt)
#pragma unroll
    for (int r = 0; r < 4; ++r) rowsum[mt][r] = 0.f;

  // ---- PASS 1: row sums ----
  for (int jt = 0; jt < 16; ++jt) {
    __syncthreads();
    stage_k(jt);
    __syncthreads();
#pragma unroll
    for (int nt = 0; nt < 2; ++nt) {
      f32x4 acc[4];
#pragma unroll
      for (int mt = 0; mt < 4; ++mt) acc[mt] = (f32x4){0.f, 0.f, 0.f, 0.f};
#pragma unroll
      for (int ks = 0; ks < 4; ++ks) {
        bf16x8 bfr = *(const bf16x8*)(
            &kt[(wave * 32 + nt * 16 + lq) * LDST + ks * 32 + quad * 8]);
#pragma unroll
        for (int mt = 0; mt < 4; ++mt)
          acc[mt] = __builtin_amdgcn_mfma_f32_16x16x32_bf16(af[mt][ks], bfr, acc[mt], 0, 0, 0);
      }
#pragma unroll
      for (int mt = 0; mt < 4; ++mt)
#pragma unroll
        for (int r = 0; r < 4; ++r) rowsum[mt][r] += fexp2(acc[mt][r]);
    }
  }
  // reduce rowsums over the 16 col-lanes
#pragma unroll
  for (int d2 = 1; d2 <= 8; d2 <<= 1)
#pragma unroll
    for (int mt = 0; mt < 4; ++mt)
#pragma unroll
      for (int r = 0; r < 4; ++r)
        rowsum[mt][r] += __shfl_xor(rowsum[mt][r], d2, 64);
  if (lq == 0) {
#pragma unroll
    for (int mt = 0; mt < 4; ++mt)
#pragma unroll
      for (int r = 0; r < 4; ++r)
        rs_lds[wave][mt * 16 + quad * 4 + r] = rowsum[mt][r];
  }
  __syncthreads();
  if (tid < 64) {
    float l = rs_lds[0][tid] + rs_lds[1][tid] + rs_lds[2][tid] + rs_lds[3][tid];
    int gi = i0 + tid;
    float z = theta[gi] - mu[gi] * t[b * SS + gi];
    float tf = 1.f / (1.f + fexp2(-z * 1.44269504f));
    c_lds[tid] = tf / l;
  }
  __syncthreads();
  float creg[4][4];
#pragma unroll
  for (int mt = 0; mt < 4; ++mt)
#pragma unroll
    for (int r = 0; r < 4; ++r) creg[mt][r] = c_lds[mt * 16 + quad * 4 + r];

  // ---- PASS 2: column sums -> w ----
  for (int jt = 0; jt < 16; ++jt) {
    __syncthreads();
    stage_k(jt);
    __syncthreads();
#pragma unroll
    for (int nt = 0; nt < 2; ++nt) {
      f32x4 acc[4];
#pragma unroll
      for (int mt = 0; mt < 4; ++mt) acc[mt] = (f32x4){0.f, 0.f, 0.f, 0.f};
#pragma unroll
      for (int ks = 0; ks < 4; ++ks) {
        bf16x8 bfr = *(const bf16x8*)(
            &kt[(wave * 32 + nt * 16 + lq) * LDST + ks * 32 + quad * 8]);
#pragma unroll
        for (int mt = 0; mt < 4; ++mt)
          acc[mt] = __builtin_amdgcn_mfma_f32_16x16x32_bf16(af[mt][ks], bfr, acc[mt], 0, 0, 0);
      }
      float cs = 0.f;
#pragma unroll
      for (int mt = 0; mt < 4; ++mt)
#pragma unroll
        for (int r = 0; r < 4; ++r) cs += creg[mt][r] * fexp2(acc[mt][r]);
      cs += __shfl_xor(cs, 16, 64);
      cs += __shfl_xor(cs, 32, 64);
      if (lane < 16)
        atomicAdd(&w[b * SS + jt * 128 + wave * 32 + nt * 16 + lane], cs);
    }
  }
}

// ---------------------------------------------------------------------------
// Kernel 3: v[b,d] = sum_j w[b,j] * x[b,j,d].  grid 16*8, block 256.
// ---------------------------------------------------------------------------
__global__ __launch_bounds__(256) void finalize(
    const float* __restrict__ x, const float* __restrict__ w,
    float* __restrict__ out) {
  const int b = blockIdx.x >> 3;
  const int j0 = (blockIdx.x & 7) * 256;
  const int tid = threadIdx.x;
  const int d = tid & 127, jo = tid >> 7;
  float acc = 0.f;
  for (int jj = 0; jj < 128; ++jj) {
    int j = j0 + jj * 2 + jo;
    acc += w[b * SS + j] * x[((size_t)b * SS + j) * DD + d];
  }
  __shared__ float red[256];
  red[tid] = acc;
  __syncthreads();
  if (tid < 128) atomicAdd(&out[b * DD + tid], red[tid] + red[tid + 128]);
}

extern "C" void kernel_launch(void* const* d_in, const int* in_sizes, int n_in,
                              void* d_out, int out_size, void* d_ws, size_t ws_size,
                              hipStream_t stream) {
  const float* x = (const float*)d_in[0];
  const float* t = (const float*)d_in[1];
  const float* Wq = (const float*)d_in[2];
  const float* Wk = (const float*)d_in[3];
  const float* theta = (const float*)d_in[4];
  const float* mu = (const float*)d_in[5];
  float* out = (float*)d_out;

  unsigned short* qb = (unsigned short*)d_ws;                   // 8.4 MB
  unsigned short* kb = qb + (size_t)BB * SS * DD;               // 8.4 MB
  float* w = (float*)(kb + (size_t)BB * SS * DD);               // 131 KB

  hipMemsetAsync(w, 0, (size_t)BB * SS * sizeof(float), stream);
  hipMemsetAsync(d_out, 0, (size_t)BB * DD * sizeof(float), stream);

  qk_gemm<<<dim3(256), dim3(256), 0, stream>>>(x, Wq, Wk, qb, kb);
  attn_ce<<<dim3(512), dim3(256), 0, stream>>>(qb, kb, t, theta, mu, w);
  finalize<<<dim3(128), dim3(256), 0, stream>>>(x, w, out);
}